// Round 1
// baseline (171.767 us; speedup 1.0000x reference)
//
#include <hip/hip_runtime.h>
#include <math.h>

// ---------------------------------------------------------------------------
// AsymQuantMatMul: A[4096,2048] fp32, B[2048,4096] fp32 -> out[4096,4096] fp32
// Pipeline: minmax -> qparams -> quantize A (row-major i8, q-128),
//           quantize B transposed (B8T[n][k] i8), row sums, i8 MFMA GEMM.
// ---------------------------------------------------------------------------

#define M_DIM 4096
#define K_DIM 2048
#define N_DIM 4096

using int4v = __attribute__((ext_vector_type(4))) int;

typedef __attribute__((address_space(1))) const void glb_cv;
typedef __attribute__((address_space(3))) void lds_v;

__device__ __forceinline__ int qbyte(float x, float s, float z) {
    // match reference: clip(round(x/scale) + zero, 0, 255), then shift by -128
    float q = fminf(fmaxf(rintf(x / s) + z, 0.0f), 255.0f);
    return (int)q - 128;
}

__device__ __forceinline__ int sum4(int w) {
    return (int)(signed char)(w) + (int)(signed char)(w >> 8) +
           (int)(signed char)(w >> 16) + (int)(signed char)(w >> 24);
}

// ---- Stage 1: per-block min/max partials (512 blocks for A, 512 for B) ----
__global__ void minmax_stage1(const float* __restrict__ A,
                              const float* __restrict__ B,
                              float* __restrict__ partials) {
    int b = blockIdx.x;
    const float* src = (b < 512) ? A : B;
    int lb = (b < 512) ? b : b - 512;
    const float4* v = (const float4*)src + (long)lb * 4096;  // 4096 float4/block
    float mn = INFINITY, mx = -INFINITY;
    for (int i = threadIdx.x; i < 4096; i += 256) {
        float4 x = v[i];
        mn = fminf(mn, fminf(fminf(x.x, x.y), fminf(x.z, x.w)));
        mx = fmaxf(mx, fmaxf(fmaxf(x.x, x.y), fmaxf(x.z, x.w)));
    }
    for (int off = 32; off; off >>= 1) {
        mn = fminf(mn, __shfl_down(mn, off));
        mx = fmaxf(mx, __shfl_down(mx, off));
    }
    __shared__ float smn[4], smx[4];
    int w = threadIdx.x >> 6;
    if ((threadIdx.x & 63) == 0) { smn[w] = mn; smx[w] = mx; }
    __syncthreads();
    if (threadIdx.x == 0) {
        mn = fminf(fminf(smn[0], smn[1]), fminf(smn[2], smn[3]));
        mx = fmaxf(fmaxf(smx[0], smx[1]), fmaxf(smx[2], smx[3]));
        partials[2 * b] = mn;
        partials[2 * b + 1] = mx;
    }
}

// ---- Stage 2: final reduce + quant params {sA, zA, sB, zB} ----
__global__ void minmax_stage2(const float* __restrict__ partials,
                              float* __restrict__ qp) {
    int t = threadIdx.x;
    float mnA = INFINITY, mxA = -INFINITY, mnB = INFINITY, mxB = -INFINITY;
    for (int i = t; i < 512; i += 256) {
        mnA = fminf(mnA, partials[2 * i]);
        mxA = fmaxf(mxA, partials[2 * i + 1]);
        mnB = fminf(mnB, partials[2 * (i + 512)]);
        mxB = fmaxf(mxB, partials[2 * (i + 512) + 1]);
    }
    for (int off = 32; off; off >>= 1) {
        mnA = fminf(mnA, __shfl_down(mnA, off));
        mxA = fmaxf(mxA, __shfl_down(mxA, off));
        mnB = fminf(mnB, __shfl_down(mnB, off));
        mxB = fmaxf(mxB, __shfl_down(mxB, off));
    }
    __shared__ float s[4][4];
    int w = t >> 6;
    if ((t & 63) == 0) { s[w][0] = mnA; s[w][1] = mxA; s[w][2] = mnB; s[w][3] = mxB; }
    __syncthreads();
    if (t == 0) {
        for (int i = 1; i < 4; i++) {
            mnA = fminf(mnA, s[i][0]); mxA = fmaxf(mxA, s[i][1]);
            mnB = fminf(mnB, s[i][2]); mxB = fmaxf(mxB, s[i][3]);
        }
        float sA = (mxA - mnA) / 255.0f;
        float zA = rintf(-mnA / sA);
        float sB = (mxB - mnB) / 255.0f;
        float zB = rintf(-mnB / sB);
        qp[0] = sA; qp[1] = zA; qp[2] = sB; qp[3] = zB;
    }
}

// ---- Quantize A: row-major [4096][2048] i8 (value = q - 128) ----
__global__ void quantA_kernel(const float* __restrict__ X,
                              signed char* __restrict__ Q,
                              const float* __restrict__ qp) {
    float s = qp[0], z = qp[1];
    long base = ((long)blockIdx.x * 256 + threadIdx.x) * 16;
    const float4* v = (const float4*)(X + base);
    union { signed char c[16]; int4 i4; } u;
#pragma unroll
    for (int j = 0; j < 4; j++) {
        float4 x = v[j];
        u.c[j * 4 + 0] = (signed char)qbyte(x.x, s, z);
        u.c[j * 4 + 1] = (signed char)qbyte(x.y, s, z);
        u.c[j * 4 + 2] = (signed char)qbyte(x.z, s, z);
        u.c[j * 4 + 3] = (signed char)qbyte(x.w, s, z);
    }
    *(int4*)(Q + base) = u.i4;
}

// ---- Quantize B transposed: B[2048][4096] -> B8T[4096][2048] i8 ----
// grid (32 k-tiles, 64 n-tiles), 64x64 tiles, transpose through LDS
__global__ void quantBT_kernel(const float* __restrict__ B,
                               signed char* __restrict__ BT,
                               const float* __restrict__ qp) {
    __shared__ __align__(16) signed char tile[64][80];  // [n][k], padded
    float s = qp[2], z = qp[3];
    int k0 = blockIdx.x * 64, n0 = blockIdx.y * 64;
    int t = threadIdx.x;
    int cn = (t & 15) * 4;  // n offset within tile
    int rk = t >> 4;        // k row 0..15
#pragma unroll
    for (int rr = 0; rr < 64; rr += 16) {
        int k = rk + rr;
        float4 x = *(const float4*)&B[(long)(k0 + k) * N_DIM + n0 + cn];
        tile[cn + 0][k] = (signed char)qbyte(x.x, s, z);
        tile[cn + 1][k] = (signed char)qbyte(x.y, s, z);
        tile[cn + 2][k] = (signed char)qbyte(x.z, s, z);
        tile[cn + 3][k] = (signed char)qbyte(x.w, s, z);
    }
    __syncthreads();
    int n2 = t >> 2, kc = (t & 3) * 16;
    *(int4*)&BT[(long)(n0 + n2) * K_DIM + k0 + kc] = *(const int4*)&tile[n2][kc];
}

// ---- Row sums: rowA[m] = sum_k A8[m][k]; colB[n] = sum_k B8T[n][k] ----
__global__ void sums_kernel(const signed char* __restrict__ A8,
                            const signed char* __restrict__ B8T,
                            int* __restrict__ rowA, int* __restrict__ colB) {
    int row = blockIdx.x * 4 + (threadIdx.x >> 6);  // 8192 rows total
    int lane = threadIdx.x & 63;
    const signed char* src = (row < 4096) ? A8 : B8T;
    int* dst = (row < 4096) ? rowA : colB;
    int r = (row < 4096) ? row : row - 4096;
    const int4* p = (const int4*)(src + (long)r * K_DIM);
    int acc = 0;
#pragma unroll
    for (int i = 0; i < 2; i++) {
        int4 w = p[lane + i * 64];
        acc += sum4(w.x) + sum4(w.y) + sum4(w.z) + sum4(w.w);
    }
    for (int off = 32; off; off >>= 1) acc += __shfl_down(acc, off);
    if (lane == 0) dst[r] = acc;
}

// ---- i8 MFMA GEMM: 128x128 tile, BK=64, 4 waves of 4x4 16x16 tiles ----
__global__ void gemm_i8(const signed char* __restrict__ A8,
                        const signed char* __restrict__ B8T,
                        const int* __restrict__ rowA,
                        const int* __restrict__ colB,
                        const float* __restrict__ qp,
                        float* __restrict__ out) {
    __shared__ __align__(16) signed char As[128 * 64];
    __shared__ __align__(16) signed char Bs[128 * 64];

    int r0 = blockIdx.y * 128;  // m tile base
    int c0 = blockIdx.x * 128;  // n tile base
    int t = threadIdx.x, lane = t & 63, wave = t >> 6;

    int4v acc[4][4];
#pragma unroll
    for (int i = 0; i < 4; i++)
#pragma unroll
        for (int j = 0; j < 4; j++) acc[i][j] = (int4v){0, 0, 0, 0};

    int wm = (wave >> 1) * 64;  // wave's m quadrant
    int wn = (wave & 1) * 64;   // wave's n quadrant
    int ca0 = wave * 128 + lane;  // first staging chunk id for this wave's lane

    int kg = (lane >> 4) * 16;  // k byte offset within fragment row
    int mrow = lane & 15;

    for (int k0 = 0; k0 < K_DIM; k0 += 64) {
        __syncthreads();  // protect LDS from previous iteration's readers
#pragma unroll
        for (int j = 0; j < 2; j++) {
            int ch = ca0 + j * 64;  // chunk id 0..511; row=ch>>2, kc=(ch&3)*16
            const signed char* ga = A8 + (long)(r0 + (ch >> 2)) * K_DIM + k0 + (ch & 3) * 16;
            __builtin_amdgcn_global_load_lds((glb_cv*)ga, (lds_v*)(As + ch * 16), 16, 0, 0);
            const signed char* gb = B8T + (long)(c0 + (ch >> 2)) * K_DIM + k0 + (ch & 3) * 16;
            __builtin_amdgcn_global_load_lds((glb_cv*)gb, (lds_v*)(Bs + ch * 16), 16, 0, 0);
        }
        __syncthreads();  // drains vmcnt: staged data visible

        int4v af[4], bf[4];
#pragma unroll
        for (int i = 0; i < 4; i++)
            af[i] = *(const int4v*)&As[(wm + i * 16 + mrow) * 64 + kg];
#pragma unroll
        for (int j = 0; j < 4; j++)
            bf[j] = *(const int4v*)&Bs[(wn + j * 16 + mrow) * 64 + kg];
#pragma unroll
        for (int i = 0; i < 4; i++)
#pragma unroll
            for (int j = 0; j < 4; j++)
                acc[i][j] = __builtin_amdgcn_mfma_i32_16x16x64_i8(af[i], bf[j], acc[i][j], 0, 0, 0);
    }

    // Epilogue: out = sA*sB*(acc + cB*rowA[m] + cA*colB[n] + K*cA*cB)
    float sA = qp[0], zA = qp[1], sB = qp[2], zB = qp[3];
    int cA = 128 - (int)zA, cB = 128 - (int)zB;
    float ss = sA * sB;
    int Kzz = K_DIM * cA * cB;
    int colb = c0 + wn + (lane & 15);
    int rquad = (lane >> 4) * 4;
#pragma unroll
    for (int i = 0; i < 4; i++) {
#pragma unroll
        for (int j = 0; j < 4; j++) {
            int cc = colb + j * 16;
            int cbn = colB[cc];
#pragma unroll
            for (int r = 0; r < 4; r++) {
                int rr = r0 + wm + i * 16 + rquad + r;
                int v = acc[i][j][r] + cB * rowA[rr] + cA * cbn + Kzz;
                out[(long)rr * N_DIM + cc] = ss * (float)v;
            }
        }
    }
}

extern "C" void kernel_launch(void* const* d_in, const int* in_sizes, int n_in,
                              void* d_out, int out_size, void* d_ws, size_t ws_size,
                              hipStream_t stream) {
    const float* A = (const float*)d_in[0];
    const float* B = (const float*)d_in[1];
    float* out = (float*)d_out;
    char* ws = (char*)d_ws;

    signed char* A8  = (signed char*)ws;                    //  8 MB
    signed char* B8T = (signed char*)(ws + 8388608);        //  8 MB
    int*   rowA      = (int*)(ws + 16777216);               // 16 KB
    int*   colB      = (int*)(ws + 16793600);               // 16 KB
    float* partials  = (float*)(ws + 16809984);             //  8 KB
    float* qp        = (float*)(ws + 16818176);             // 16 B

    minmax_stage1<<<1024, 256, 0, stream>>>(A, B, partials);
    minmax_stage2<<<1, 256, 0, stream>>>(partials, qp);
    quantA_kernel<<<2048, 256, 0, stream>>>(A, A8, qp);
    quantBT_kernel<<<dim3(32, 64), 256, 0, stream>>>(B, B8T, qp);
    sums_kernel<<<2048, 256, 0, stream>>>(A8, B8T, rowA, colB);
    gemm_i8<<<dim3(32, 32), 256, 0, stream>>>(A8, B8T, rowA, colB, qp, out);
}

// Round 2
// 170.022 us; speedup vs baseline: 1.0103x; 1.0103x over previous
//
#include <hip/hip_runtime.h>
#include <math.h>

// ---------------------------------------------------------------------------
// AsymQuantMatMul: A[4096,2048] fp32, B[2048,4096] fp32 -> out[4096,4096] fp32
// R1: GEMM 256x128 block, 128x64 per-wave tile (8x4 frags), XOR-swizzled LDS
//     (kills 8-way ds_read_b128 bank conflicts); rowsum fused into quantA,
//     colsum fused into quantBT via atomics (zeroed in minmax_stage2).
// ---------------------------------------------------------------------------

#define M_DIM 4096
#define K_DIM 2048
#define N_DIM 4096

using int4v = __attribute__((ext_vector_type(4))) int;

typedef __attribute__((address_space(1))) const void glb_cv;
typedef __attribute__((address_space(3))) void lds_v;

__device__ __forceinline__ int qbyte(float x, float s, float z) {
    // match reference: clip(round(x/scale) + zero, 0, 255), then shift by -128
    float q = fminf(fmaxf(rintf(x / s) + z, 0.0f), 255.0f);
    return (int)q - 128;
}

__device__ __forceinline__ int sum4(int w) {
    return (int)(signed char)(w) + (int)(signed char)(w >> 8) +
           (int)(signed char)(w >> 16) + (int)(signed char)(w >> 24);
}

// ---- Stage 1: per-block min/max partials (512 blocks for A, 512 for B) ----
__global__ void minmax_stage1(const float* __restrict__ A,
                              const float* __restrict__ B,
                              float* __restrict__ partials) {
    int b = blockIdx.x;
    const float* src = (b < 512) ? A : B;
    int lb = (b < 512) ? b : b - 512;
    const float4* v = (const float4*)src + (long)lb * 4096;  // 4096 float4/block
    float mn = INFINITY, mx = -INFINITY;
    for (int i = threadIdx.x; i < 4096; i += 256) {
        float4 x = v[i];
        mn = fminf(mn, fminf(fminf(x.x, x.y), fminf(x.z, x.w)));
        mx = fmaxf(mx, fmaxf(fmaxf(x.x, x.y), fmaxf(x.z, x.w)));
    }
    for (int off = 32; off; off >>= 1) {
        mn = fminf(mn, __shfl_down(mn, off));
        mx = fmaxf(mx, __shfl_down(mx, off));
    }
    __shared__ float smn[4], smx[4];
    int w = threadIdx.x >> 6;
    if ((threadIdx.x & 63) == 0) { smn[w] = mn; smx[w] = mx; }
    __syncthreads();
    if (threadIdx.x == 0) {
        mn = fminf(fminf(smn[0], smn[1]), fminf(smn[2], smn[3]));
        mx = fmaxf(fmaxf(smx[0], smx[1]), fmaxf(smx[2], smx[3]));
        partials[2 * b] = mn;
        partials[2 * b + 1] = mx;
    }
}

// ---- Stage 2: final reduce + quant params {sA, zA, sB, zB}; zero colB ----
__global__ void minmax_stage2(const float* __restrict__ partials,
                              float* __restrict__ qp,
                              int* __restrict__ colB) {
    int t = threadIdx.x;
    for (int i = t; i < N_DIM; i += 256) colB[i] = 0;  // init for atomics
    float mnA = INFINITY, mxA = -INFINITY, mnB = INFINITY, mxB = -INFINITY;
    for (int i = t; i < 512; i += 256) {
        mnA = fminf(mnA, partials[2 * i]);
        mxA = fmaxf(mxA, partials[2 * i + 1]);
        mnB = fminf(mnB, partials[2 * (i + 512)]);
        mxB = fmaxf(mxB, partials[2 * (i + 512) + 1]);
    }
    for (int off = 32; off; off >>= 1) {
        mnA = fminf(mnA, __shfl_down(mnA, off));
        mxA = fmaxf(mxA, __shfl_down(mxA, off));
        mnB = fminf(mnB, __shfl_down(mnB, off));
        mxB = fmaxf(mxB, __shfl_down(mxB, off));
    }
    __shared__ float s[4][4];
    int w = t >> 6;
    if ((t & 63) == 0) { s[w][0] = mnA; s[w][1] = mxA; s[w][2] = mnB; s[w][3] = mxB; }
    __syncthreads();
    if (t == 0) {
        for (int i = 1; i < 4; i++) {
            mnA = fminf(mnA, s[i][0]); mxA = fmaxf(mxA, s[i][1]);
            mnB = fminf(mnB, s[i][2]); mxB = fmaxf(mxB, s[i][3]);
        }
        float sA = (mxA - mnA) / 255.0f;
        float zA = rintf(-mnA / sA);
        float sB = (mxB - mnB) / 255.0f;
        float zB = rintf(-mnB / sB);
        qp[0] = sA; qp[1] = zA; qp[2] = sB; qp[3] = zB;
    }
}

// ---- Quantize A (+ fused row sums): block = 2 rows of 2048 ----
__global__ void quantA_kernel(const float* __restrict__ X,
                              signed char* __restrict__ Q,
                              const float* __restrict__ qp,
                              int* __restrict__ rowA) {
    float s = qp[0], z = qp[1];
    int t = threadIdx.x;
    long base = (long)blockIdx.x * 4096 + (long)t * 16;
    const float4* v = (const float4*)(X + base);
    union { signed char c[16]; int4 i4; } u;
    int ls = 0;
#pragma unroll
    for (int j = 0; j < 4; j++) {
        float4 x = v[j];
        int q0 = qbyte(x.x, s, z), q1 = qbyte(x.y, s, z);
        int q2 = qbyte(x.z, s, z), q3 = qbyte(x.w, s, z);
        u.c[j * 4 + 0] = (signed char)q0;
        u.c[j * 4 + 1] = (signed char)q1;
        u.c[j * 4 + 2] = (signed char)q2;
        u.c[j * 4 + 3] = (signed char)q3;
        ls += q0 + q1 + q2 + q3;
    }
    *(int4*)(Q + base) = u.i4;
    // reduce: threads 0-127 -> row 2b, threads 128-255 -> row 2b+1
    for (int off = 32; off; off >>= 1) ls += __shfl_down(ls, off);
    __shared__ int ws[4];
    if ((t & 63) == 0) ws[t >> 6] = ls;
    __syncthreads();
    if (t == 0) rowA[blockIdx.x * 2] = ws[0] + ws[1];
    if (t == 128) rowA[blockIdx.x * 2 + 1] = ws[2] + ws[3];
}

// ---- Quantize B transposed (+ fused col sums via atomics) ----
// grid (32 k-tiles, 64 n-tiles), 64x64 tiles, transpose through LDS
__global__ void quantBT_kernel(const float* __restrict__ B,
                               signed char* __restrict__ BT,
                               const float* __restrict__ qp,
                               int* __restrict__ colB) {
    __shared__ __align__(16) signed char tile[64][80];  // [n][k], padded
    float s = qp[2], z = qp[3];
    int k0 = blockIdx.x * 64, n0 = blockIdx.y * 64;
    int t = threadIdx.x;
    int cn = (t & 15) * 4;  // n offset within tile
    int rk = t >> 4;        // k row 0..15
#pragma unroll
    for (int rr = 0; rr < 64; rr += 16) {
        int k = rk + rr;
        float4 x = *(const float4*)&B[(long)(k0 + k) * N_DIM + n0 + cn];
        tile[cn + 0][k] = (signed char)qbyte(x.x, s, z);
        tile[cn + 1][k] = (signed char)qbyte(x.y, s, z);
        tile[cn + 2][k] = (signed char)qbyte(x.z, s, z);
        tile[cn + 3][k] = (signed char)qbyte(x.w, s, z);
    }
    __syncthreads();
    int n2 = t >> 2, kc = (t & 3) * 16;
    int4 w = *(const int4*)&tile[n2][kc];
    *(int4*)&BT[(long)(n0 + n2) * K_DIM + k0 + kc] = w;
    int ls = sum4(w.x) + sum4(w.y) + sum4(w.z) + sum4(w.w);
    ls += __shfl_down(ls, 2);
    ls += __shfl_down(ls, 1);
    if ((t & 3) == 0) atomicAdd(&colB[n0 + n2], ls);
}

// ---- i8 MFMA GEMM: 256x128 block, 4 waves each 128x64 (8x4 frag tiles) ----
// LDS XOR swizzle: 16B chunk column c of row r holds global k-chunk
// c ^ ((r>>1)&3)  -> fragment ds_read_b128 spreads 16 lanes over all 32 banks.
__global__ __launch_bounds__(256, 2) void gemm_i8(
        const signed char* __restrict__ A8,
        const signed char* __restrict__ B8T,
        const int* __restrict__ rowA,
        const int* __restrict__ colB,
        const float* __restrict__ qp,
        float* __restrict__ out) {
    __shared__ __align__(16) signed char As[256 * 64];  // 16 KB
    __shared__ __align__(16) signed char Bs[128 * 64];  //  8 KB

    int r0 = blockIdx.y * 256;  // m tile base
    int c0 = blockIdx.x * 128;  // n tile base
    int t = threadIdx.x, lane = t & 63, wave = t >> 6;

    int4v acc[8][4];
#pragma unroll
    for (int i = 0; i < 8; i++)
#pragma unroll
        for (int j = 0; j < 4; j++) acc[i][j] = (int4v){0, 0, 0, 0};

    int wm = (wave >> 1) * 128;  // wave's m half
    int wn = (wave & 1) * 64;    // wave's n half
    int mrow = lane & 15;
    int g = lane >> 4;                       // k-group 0..3
    int kq = ((g ^ ((mrow >> 1) & 3)) * 16); // swizzled k byte offset

    // Precompute per-thread staging offsets (row, swizzled k-chunk)
    long aoff[4], boff[2];
#pragma unroll
    for (int j = 0; j < 4; j++) {
        int ch = t + 256 * j;            // A chunk 0..1023
        int row = ch >> 2, c = ch & 3;
        int gk = c ^ ((row >> 1) & 3);
        aoff[j] = (long)(r0 + row) * K_DIM + gk * 16;
    }
#pragma unroll
    for (int j = 0; j < 2; j++) {
        int ch = t + 256 * j;            // B chunk 0..511
        int row = ch >> 2, c = ch & 3;
        int gk = c ^ ((row >> 1) & 3);
        boff[j] = (long)(c0 + row) * K_DIM + gk * 16;
    }

    for (int k0 = 0; k0 < K_DIM; k0 += 64) {
        __syncthreads();  // protect LDS from previous iteration's readers
#pragma unroll
        for (int j = 0; j < 4; j++)
            __builtin_amdgcn_global_load_lds((glb_cv*)(A8 + aoff[j] + k0),
                                             (lds_v*)(As + (t + 256 * j) * 16), 16, 0, 0);
#pragma unroll
        for (int j = 0; j < 2; j++)
            __builtin_amdgcn_global_load_lds((glb_cv*)(B8T + boff[j] + k0),
                                             (lds_v*)(Bs + (t + 256 * j) * 16), 16, 0, 0);
        __syncthreads();  // drains vmcnt: staged data visible

        int4v af[8], bf[4];
#pragma unroll
        for (int i = 0; i < 8; i++)
            af[i] = *(const int4v*)&As[(wm + i * 16 + mrow) * 64 + kq];
#pragma unroll
        for (int j = 0; j < 4; j++)
            bf[j] = *(const int4v*)&Bs[(wn + j * 16 + mrow) * 64 + kq];
#pragma unroll
        for (int i = 0; i < 8; i++)
#pragma unroll
            for (int j = 0; j < 4; j++)
                acc[i][j] = __builtin_amdgcn_mfma_i32_16x16x64_i8(af[i], bf[j], acc[i][j], 0, 0, 0);
    }

    // Epilogue: out = sA*sB*(acc + cB*rowA[m] + cA*colB[n] + K*cA*cB)
    float sA = qp[0], zA = qp[1], sB = qp[2], zB = qp[3];
    int cA = 128 - (int)zA, cB = 128 - (int)zB;
    float ss = sA * sB;
    int Kzz = K_DIM * cA * cB;
    int ocol = c0 + wn + mrow;
    int orow = r0 + wm + g * 4;
#pragma unroll
    for (int i = 0; i < 8; i++) {
        int ra[4];
#pragma unroll
        for (int r = 0; r < 4; r++) ra[r] = cB * rowA[orow + i * 16 + r] + Kzz;
#pragma unroll
        for (int j = 0; j < 4; j++) {
            int cc = ocol + j * 16;
            int can = cA * colB[cc];
#pragma unroll
            for (int r = 0; r < 4; r++) {
                int v = acc[i][j][r] + ra[r] + can;
                out[(long)(orow + i * 16 + r) * N_DIM + cc] = ss * (float)v;
            }
        }
    }
}

extern "C" void kernel_launch(void* const* d_in, const int* in_sizes, int n_in,
                              void* d_out, int out_size, void* d_ws, size_t ws_size,
                              hipStream_t stream) {
    const float* A = (const float*)d_in[0];
    const float* B = (const float*)d_in[1];
    float* out = (float*)d_out;
    char* ws = (char*)d_ws;

    signed char* A8  = (signed char*)ws;                    //  8 MB
    signed char* B8T = (signed char*)(ws + 8388608);        //  8 MB
    int*   rowA      = (int*)(ws + 16777216);               // 16 KB
    int*   colB      = (int*)(ws + 16793600);               // 16 KB
    float* partials  = (float*)(ws + 16809984);             //  8 KB
    float* qp        = (float*)(ws + 16818176);             // 16 B

    minmax_stage1<<<1024, 256, 0, stream>>>(A, B, partials);
    minmax_stage2<<<1, 256, 0, stream>>>(partials, qp, colB);
    quantA_kernel<<<2048, 256, 0, stream>>>(A, A8, qp, rowA);
    quantBT_kernel<<<dim3(32, 64), 256, 0, stream>>>(B, B8T, qp, colB);
    gemm_i8<<<dim3(32, 16), 256, 0, stream>>>(A8, B8T, rowA, colB, qp, out);
}

// Round 3
// 162.875 us; speedup vs baseline: 1.0546x; 1.0439x over previous
//
#include <hip/hip_runtime.h>
#include <math.h>

// ---------------------------------------------------------------------------
// AsymQuantMatMul: A[4096,2048] fp32, B[2048,4096] fp32 -> out[4096,4096] fp32
// R2: GEMM 128x128 block (grid 1024, 3 blocks/CU), BK=128 (16 K-iters),
//     3-bit XOR LDS swizzle, XCD-aware L2 block regioning. Quant kernels use
//     reciprocal multiply; quantBT transposes via int-packed LDS (2-way max).
// ---------------------------------------------------------------------------

#define M_DIM 4096
#define K_DIM 2048
#define N_DIM 4096

using int4v = __attribute__((ext_vector_type(4))) int;

typedef __attribute__((address_space(1))) const void glb_cv;
typedef __attribute__((address_space(3))) void lds_v;

__device__ __forceinline__ int qbyte(float x, float rs, float z) {
    // reference: clip(round(x/scale) + zero, 0, 255), shifted by -128
    float q = fminf(fmaxf(rintf(x * rs) + z, 0.0f), 255.0f);
    return (int)q - 128;
}

__device__ __forceinline__ int sum4(int w) {
    return (int)(signed char)(w) + (int)(signed char)(w >> 8) +
           (int)(signed char)(w >> 16) + (int)(signed char)(w >> 24);
}

// ---- Stage 1: per-block min/max partials (512 blocks for A, 512 for B) ----
__global__ void minmax_stage1(const float* __restrict__ A,
                              const float* __restrict__ B,
                              float* __restrict__ partials) {
    int b = blockIdx.x;
    const float* src = (b < 512) ? A : B;
    int lb = (b < 512) ? b : b - 512;
    const float4* v = (const float4*)src + (long)lb * 4096;  // 4096 float4/block
    float mn = INFINITY, mx = -INFINITY;
    for (int i = threadIdx.x; i < 4096; i += 256) {
        float4 x = v[i];
        mn = fminf(mn, fminf(fminf(x.x, x.y), fminf(x.z, x.w)));
        mx = fmaxf(mx, fmaxf(fmaxf(x.x, x.y), fmaxf(x.z, x.w)));
    }
    for (int off = 32; off; off >>= 1) {
        mn = fminf(mn, __shfl_down(mn, off));
        mx = fmaxf(mx, __shfl_down(mx, off));
    }
    __shared__ float smn[4], smx[4];
    int w = threadIdx.x >> 6;
    if ((threadIdx.x & 63) == 0) { smn[w] = mn; smx[w] = mx; }
    __syncthreads();
    if (threadIdx.x == 0) {
        mn = fminf(fminf(smn[0], smn[1]), fminf(smn[2], smn[3]));
        mx = fmaxf(fmaxf(smx[0], smx[1]), fmaxf(smx[2], smx[3]));
        partials[2 * b] = mn;
        partials[2 * b + 1] = mx;
    }
}

// ---- Stage 2: final reduce + qp {sA,zA,sB,zB,1/sA,1/sB}; zero colB ----
__global__ void minmax_stage2(const float* __restrict__ partials,
                              float* __restrict__ qp,
                              int* __restrict__ colB) {
    int t = threadIdx.x;
    for (int i = t; i < N_DIM; i += 256) colB[i] = 0;  // init for atomics
    float mnA = INFINITY, mxA = -INFINITY, mnB = INFINITY, mxB = -INFINITY;
    for (int i = t; i < 512; i += 256) {
        mnA = fminf(mnA, partials[2 * i]);
        mxA = fmaxf(mxA, partials[2 * i + 1]);
        mnB = fminf(mnB, partials[2 * (i + 512)]);
        mxB = fmaxf(mxB, partials[2 * (i + 512) + 1]);
    }
    for (int off = 32; off; off >>= 1) {
        mnA = fminf(mnA, __shfl_down(mnA, off));
        mxA = fmaxf(mxA, __shfl_down(mxA, off));
        mnB = fminf(mnB, __shfl_down(mnB, off));
        mxB = fmaxf(mxB, __shfl_down(mxB, off));
    }
    __shared__ float s[4][4];
    int w = t >> 6;
    if ((t & 63) == 0) { s[w][0] = mnA; s[w][1] = mxA; s[w][2] = mnB; s[w][3] = mxB; }
    __syncthreads();
    if (t == 0) {
        for (int i = 1; i < 4; i++) {
            mnA = fminf(mnA, s[i][0]); mxA = fmaxf(mxA, s[i][1]);
            mnB = fminf(mnB, s[i][2]); mxB = fmaxf(mxB, s[i][3]);
        }
        float sA = (mxA - mnA) / 255.0f;
        float zA = rintf(-mnA / sA);
        float sB = (mxB - mnB) / 255.0f;
        float zB = rintf(-mnB / sB);
        qp[0] = sA; qp[1] = zA; qp[2] = sB; qp[3] = zB;
        qp[4] = 1.0f / sA; qp[5] = 1.0f / sB;
    }
}

// ---- Quantize A (+ fused row sums): block = 2 rows of 2048 ----
__global__ void quantA_kernel(const float* __restrict__ X,
                              signed char* __restrict__ Q,
                              const float* __restrict__ qp,
                              int* __restrict__ rowA) {
    float rs = qp[4], z = qp[1];
    int t = threadIdx.x;
    long base = (long)blockIdx.x * 4096 + (long)t * 16;
    const float4* v = (const float4*)(X + base);
    union { signed char c[16]; int4 i4; } u;
    int ls = 0;
#pragma unroll
    for (int j = 0; j < 4; j++) {
        float4 x = v[j];
        int q0 = qbyte(x.x, rs, z), q1 = qbyte(x.y, rs, z);
        int q2 = qbyte(x.z, rs, z), q3 = qbyte(x.w, rs, z);
        u.c[j * 4 + 0] = (signed char)q0;
        u.c[j * 4 + 1] = (signed char)q1;
        u.c[j * 4 + 2] = (signed char)q2;
        u.c[j * 4 + 3] = (signed char)q3;
        ls += q0 + q1 + q2 + q3;
    }
    *(int4*)(Q + base) = u.i4;
    for (int off = 32; off; off >>= 1) ls += __shfl_down(ls, off);
    __shared__ int ws[4];
    if ((t & 63) == 0) ws[t >> 6] = ls;
    __syncthreads();
    if (t == 0) rowA[blockIdx.x * 2] = ws[0] + ws[1];
    if (t == 128) rowA[blockIdx.x * 2 + 1] = ws[2] + ws[3];
}

// ---- Quantize B transposed (+ fused col sums) ----
// 64x64 tiles; lane packs 4 k-bytes per int -> int LDS (<=2-way, free).
__global__ void quantBT_kernel(const float* __restrict__ B,
                               signed char* __restrict__ BT,
                               const float* __restrict__ qp,
                               int* __restrict__ colB) {
    __shared__ int tile[64][17];  // [n][k/4], +1 pad
    float rs = qp[5], z = qp[3];
    int k0 = blockIdx.x * 64, n0 = blockIdx.y * 64;
    int t = threadIdx.x;
    int cn = (t & 15) * 4;  // n offset within tile
    int kg = (t >> 4) * 4;  // k offset within tile
    int w0 = 0, w1 = 0, w2 = 0, w3 = 0;
#pragma unroll
    for (int r = 0; r < 4; r++) {
        float4 x = *(const float4*)&B[(long)(k0 + kg + r) * N_DIM + n0 + cn];
        w0 |= (qbyte(x.x, rs, z) & 255) << (8 * r);
        w1 |= (qbyte(x.y, rs, z) & 255) << (8 * r);
        w2 |= (qbyte(x.z, rs, z) & 255) << (8 * r);
        w3 |= (qbyte(x.w, rs, z) & 255) << (8 * r);
    }
    int kc = kg >> 2;
    tile[cn + 0][kc] = w0;
    tile[cn + 1][kc] = w1;
    tile[cn + 2][kc] = w2;
    tile[cn + 3][kc] = w3;
    __syncthreads();
    int n2 = t >> 2, kb = (t & 3) * 4;
    int4 v;
    v.x = tile[n2][kb + 0];
    v.y = tile[n2][kb + 1];
    v.z = tile[n2][kb + 2];
    v.w = tile[n2][kb + 3];
    *(int4*)&BT[(long)(n0 + n2) * K_DIM + k0 + (t & 3) * 16] = v;
    int ls = sum4(v.x) + sum4(v.y) + sum4(v.z) + sum4(v.w);
    ls += __shfl_down(ls, 2);
    ls += __shfl_down(ls, 1);
    if ((t & 3) == 0) atomicAdd(&colB[n0 + n2], ls);
}

// ---- i8 MFMA GEMM: 128x128 block, BK=128, 4 waves each 64x64 (4x4 frags) --
// LDS: 16B chunk c of row r stored at slot c ^ (r&7) (full 3-bit XOR; row
// stride 128B == 32 banks, so the XOR alone must spread 8 slots x 4 banks).
// Block->tile mapping: 16 regions of 8x8 tiles; region = xcd + 8*(i/64) so
// each XCD works a 1024x1024 output region (2MB A8 + 2MB B8T fits its L2).
__global__ __launch_bounds__(256, 3) void gemm_i8(
        const signed char* __restrict__ A8,
        const signed char* __restrict__ B8T,
        const int* __restrict__ rowA,
        const int* __restrict__ colB,
        const float* __restrict__ qp,
        float* __restrict__ out) {
    __shared__ __align__(16) signed char As[128 * 128];  // 16 KB
    __shared__ __align__(16) signed char Bs[128 * 128];  // 16 KB

    // L2-locality block swizzle
    int b = blockIdx.x;
    int xcd = b & 7, i0 = b >> 3;
    int r = xcd + 8 * (i0 >> 6);      // region 0..15
    int j = i0 & 63;                  // 0..63 within region
    int mt = (r >> 2) * 8 + (j >> 3);
    int nt = (r & 3) * 8 + (j & 7);
    int r0 = mt * 128, c0 = nt * 128;

    int t = threadIdx.x, lane = t & 63, wave = t >> 6;
    int mrow = lane & 15;
    int g = lane >> 4;               // k-group 0..3
    int wm = (wave >> 1) * 64;       // wave m offset
    int wn = (wave & 1) * 64;        // wave n offset

    int4v acc[4][4];
#pragma unroll
    for (int i = 0; i < 4; i++)
#pragma unroll
        for (int jj = 0; jj < 4; jj++) acc[i][jj] = (int4v){0, 0, 0, 0};

    // Staging source offsets: chunk ch -> row=ch>>3, slot p=ch&7 holds
    // global chunk p^(row&7).
    long aoff[4], boff[4];
#pragma unroll
    for (int jj = 0; jj < 4; jj++) {
        int ch = t + 256 * jj;       // 0..1023
        int row = ch >> 3, p = ch & 7;
        int gk = p ^ (row & 7);
        aoff[jj] = (long)(r0 + row) * K_DIM + gk * 16;
        boff[jj] = (long)(c0 + row) * K_DIM + gk * 16;
    }

    int swz = (mrow & 7);            // read-side XOR

    for (int k0 = 0; k0 < K_DIM; k0 += 128) {
        __syncthreads();  // protect LDS from previous iteration's readers
#pragma unroll
        for (int jj = 0; jj < 4; jj++)
            __builtin_amdgcn_global_load_lds((glb_cv*)(A8 + aoff[jj] + k0),
                                             (lds_v*)(As + (t + 256 * jj) * 16), 16, 0, 0);
#pragma unroll
        for (int jj = 0; jj < 4; jj++)
            __builtin_amdgcn_global_load_lds((glb_cv*)(B8T + boff[jj] + k0),
                                             (lds_v*)(Bs + (t + 256 * jj) * 16), 16, 0, 0);
        __syncthreads();  // staged data visible

#pragma unroll
        for (int ks = 0; ks < 2; ks++) {
            int c = ks * 4 + g;
            int koff = (c ^ swz) * 16;
            int4v af[4], bf[4];
#pragma unroll
            for (int i = 0; i < 4; i++)
                af[i] = *(const int4v*)&As[(wm + i * 16 + mrow) * 128 + koff];
#pragma unroll
            for (int jj = 0; jj < 4; jj++)
                bf[jj] = *(const int4v*)&Bs[(wn + jj * 16 + mrow) * 128 + koff];
#pragma unroll
            for (int i = 0; i < 4; i++)
#pragma unroll
                for (int jj = 0; jj < 4; jj++)
                    acc[i][jj] = __builtin_amdgcn_mfma_i32_16x16x64_i8(af[i], bf[jj], acc[i][jj], 0, 0, 0);
        }
    }

    // Epilogue: out = sA*sB*(acc + cB*rowA[m] + cA*colB[n] + K*cA*cB)
    float sA = qp[0], zA = qp[1], sB = qp[2], zB = qp[3];
    int cA = 128 - (int)zA, cB = 128 - (int)zB;
    float ss = sA * sB;
    int Kzz = K_DIM * cA * cB;
    int ocol = c0 + wn + mrow;
    int orow = r0 + wm + g * 4;
#pragma unroll
    for (int i = 0; i < 4; i++) {
        int ra[4];
#pragma unroll
        for (int rr = 0; rr < 4; rr++) ra[rr] = cB * rowA[orow + i * 16 + rr] + Kzz;
#pragma unroll
        for (int jj = 0; jj < 4; jj++) {
            int cc = ocol + jj * 16;
            int can = cA * colB[cc];
#pragma unroll
            for (int rr = 0; rr < 4; rr++) {
                int v = acc[i][jj][rr] + ra[rr] + can;
                out[(long)(orow + i * 16 + rr) * N_DIM + cc] = ss * (float)v;
            }
        }
    }
}

extern "C" void kernel_launch(void* const* d_in, const int* in_sizes, int n_in,
                              void* d_out, int out_size, void* d_ws, size_t ws_size,
                              hipStream_t stream) {
    const float* A = (const float*)d_in[0];
    const float* B = (const float*)d_in[1];
    float* out = (float*)d_out;
    char* ws = (char*)d_ws;

    signed char* A8  = (signed char*)ws;                    //  8 MB
    signed char* B8T = (signed char*)(ws + 8388608);        //  8 MB
    int*   rowA      = (int*)(ws + 16777216);               // 16 KB
    int*   colB      = (int*)(ws + 16793600);               // 16 KB
    float* partials  = (float*)(ws + 16809984);             //  8 KB
    float* qp        = (float*)(ws + 16818176);             // 24 B

    minmax_stage1<<<1024, 256, 0, stream>>>(A, B, partials);
    minmax_stage2<<<1, 256, 0, stream>>>(partials, qp, colB);
    quantA_kernel<<<2048, 256, 0, stream>>>(A, A8, qp, rowA);
    quantBT_kernel<<<dim3(32, 64), 256, 0, stream>>>(B, B8T, qp, colB);
    gemm_i8<<<1024, 256, 0, stream>>>(A8, B8T, rowA, colB, qp, out);
}